// Round 4
// baseline (1067.195 us; speedup 1.0000x reference)
//
#include <hip/hip_runtime.h>

#define N_NODES 2048
#define C_CH    128
#define N_SPEC  10

#define NTRI 45            // (b<=j) pairs
#define NM3  (9 * NTRI)    // 405 symmetric cubic monomial rows

// ws layout: counts @0 (16 ints), lists @64B (10*2048 ints), Up @ float ofs 32768
#define WS_UP_OFF 32768
#define UPA_SZ 4096        // 9*45*1*10 = 4050, padded
#define UPB_SZ 13376       // 9*45*3*11 = 13365, padded
// UPC: 9*45*5*13 = 26325

// ---------------------------------------------------------------------------
// Kernel 1: bucket nodes by species.
// ---------------------------------------------------------------------------
__global__ __launch_bounds__(1024) void bucket_kernel(const int* __restrict__ index,
                                                      int* __restrict__ counts,
                                                      int* __restrict__ lists) {
    __shared__ int sc[N_SPEC];
    const int tid = threadIdx.x;
    if (tid < N_SPEC) sc[tid] = 0;
    __syncthreads();
    for (int n = tid; n < N_NODES; n += blockDim.x) {
        int s = index[n];
        int pos = atomicAdd(&sc[s], 1);
        lists[s * N_NODES + pos] = n;
    }
    __syncthreads();
    if (tid < N_SPEC) counts[tid] = sc[tid];
}

// ---------------------------------------------------------------------------
// Kernel 2: presymmetrize U3 over its (b,j) slots. c- and s-independent.
// Output layout: Up[((a*45 + t)*R + il)*M + k]   (k contiguous for the dot)
// ---------------------------------------------------------------------------
template <int M, int R>
__device__ __forceinline__ void presym_elem(const float* __restrict__ u,
                                            float* __restrict__ up, int e) {
    int k  = e % M;
    int r1 = e / M;
    int il = r1 % R;
    int r2 = r1 / R;
    int t  = r2 % NTRI;
    int a  = r2 / NTRI;
    int b = 0, j = 0, acc = 0;
    for (int bb = 0; bb < 9; ++bb) {
        int len = 9 - bb;
        if (t < acc + len) { b = bb; j = bb + (t - acc); break; }
        acc += len;
    }
    float v = u[(((a * 9 + b) * 9 + j) * M + k) * R + il];
    if (j != b) v += u[(((a * 9 + j) * 9 + b) * M + k) * R + il];
    up[e] = v;
}

__global__ __launch_bounds__(256) void presym_kernel(const float* __restrict__ u0,
                                                     const float* __restrict__ u1,
                                                     const float* __restrict__ u2,
                                                     float* __restrict__ ws) {
    int g = blockIdx.x * 256 + threadIdx.x;
    if (g < 4050)               presym_elem<10, 1>(u0, ws, g);
    else if (g < 4050 + 13365)  presym_elem<11, 3>(u1, ws + UPA_SZ, g - 4050);
    else if (g < 43740)         presym_elem<13, 5>(u2, ws + UPA_SZ + UPB_SZ, g - 17415);
}

// ---------------------------------------------------------------------------
struct Params {
    const float* U2[3]; const float* W2[3];
    const float* U1[3]; const float* W1[3];
    const float* W3[3];
};

// dot with u stride 1 (symmetrized layout), w stride C_CH (wave-uniform -> s_load)
template <int M>
__device__ __forceinline__ float dotk(const float* __restrict__ up, const float* __restrict__ wp) {
    float acc = 0.f;
#pragma unroll
    for (int k = 0; k < M; ++k) acc = __builtin_fmaf(up[k], wp[k * C_CH], acc);
    return acc;
}
// dot with u stride R (original U2/U1 layout)
template <int M, int R>
__device__ __forceinline__ float dotc(const float* __restrict__ up, const float* __restrict__ wp) {
    float acc = 0.f;
#pragma unroll
    for (int k = 0; k < M; ++k) acc = __builtin_fmaf(up[k * R], wp[k * C_CH], acc);
    return acc;
}

__device__ __forceinline__ unsigned short f2bf(float f) {   // RNE f32->bf16
    unsigned u = __float_as_uint(f);
    unsigned r = ((u >> 16) & 1u) + 0x7fffu;
    return (unsigned short)((u + r) >> 16);
}
__device__ __forceinline__ float bf_lo(unsigned u) { return __uint_as_float(u << 16); }
__device__ __forceinline__ float bf_hi(unsigned u) { return __uint_as_float(u & 0xffff0000u); }
__device__ __forceinline__ float bf_up(unsigned short h) { return __uint_as_float(((unsigned)h) << 16); }

__device__ __forceinline__ float selx(const float x[9], int a) {
    float r = x[0];
    r = (a == 1) ? x[1] : r;
    r = (a == 2) ? x[2] : r;
    r = (a == 3) ? x[3] : r;
    r = (a == 4) ? x[4] : r;
    r = (a == 5) ? x[5] : r;
    r = (a == 6) ? x[6] : r;
    r = (a == 7) ? x[7] : r;
    r = (a == 8) ? x[8] : r;
    return r;
}

__host__ __device__ constexpr int tri(int b, int j) { return b * 9 - (b * (b - 1)) / 2 + (j - b); }

// ---------------------------------------------------------------------------
// Kernel 3: fused build + eval. Block = 1 wave (64 threads) per (s, c, half).
// C3 symmetrized over (b,j): 405 bf16 rows in LDS. 2 nodes/thread.
// ---------------------------------------------------------------------------
__global__ __launch_bounds__(64, 4) void eval_kernel(const float* __restrict__ nf,
                                                     const int* __restrict__ counts,
                                                     const int* __restrict__ lists,
                                                     const float* __restrict__ Up,
                                                     Params p,
                                                     float* __restrict__ out) {
    __shared__ __align__(16) unsigned short sC3[NM3 * 8];   // bf16 [m][i0..7]
    __shared__ __align__(4)  unsigned short sC3b[NM3 + 3];  // bf16 [m] i==8
    __shared__ __align__(16) unsigned short sC2[81 * 8];    // bf16 [ab][i0..7]
    __shared__ __align__(4)  unsigned short sC2b[84];       // bf16 [ab] i==8
    __shared__ __align__(16) float sC1[9 * 8];              // f32
    __shared__ float sC1b[9];
    // LDS ~9.1 KB

    const int bi = blockIdx.x;
    const int s = bi % N_SPEC;
    const int c = (bi / N_SPEC) % C_CH;
    const int h = bi / (N_SPEC * C_CH);   // node half: 0 or 1
    const int tid = threadIdx.x;

    const float* UpA = Up;
    const float* UpB = Up + UPA_SZ;
    const float* UpC = Up + UPA_SZ + UPB_SZ;
    const float* w30 = p.W3[0] + (s * 10) * C_CH + c;
    const float* w31 = p.W3[1] + (s * 11) * C_CH + c;
    const float* w32 = p.W3[2] + (s * 13) * C_CH + c;

    // ---- build symmetrized C3 (bf16) ----
    for (int e = tid; e < NM3 * 9; e += 64) {
        int m = e / 9; int i = e - m * 9;
        float v;
        if (i == 0)     v = dotk<10>(UpA + m * 10,                w30);
        else if (i < 4) v = dotk<11>(UpB + (m * 3 + (i - 1)) * 11, w31);
        else            v = dotk<13>(UpC + (m * 5 + (i - 4)) * 13, w32);
        if (i < 8) sC3[m * 8 + i] = f2bf(v); else sC3b[m] = f2bf(v);
    }
    // ---- build C2 (bf16) ----
    for (int e = tid; e < 729; e += 64) {
        int ab = e / 9; int i = e - ab * 9;
        float v;
        if (i == 0)     v = dotc<3, 1>(p.U2[0] + ab * 3,            p.W2[0] + (s * 3) * C_CH + c);
        else if (i < 4) v = dotc<2, 3>(p.U2[1] + ab * 6 + (i - 1),  p.W2[1] + (s * 2) * C_CH + c);
        else            v = dotc<3, 5>(p.U2[2] + ab * 15 + (i - 4), p.W2[2] + (s * 3) * C_CH + c);
        if (i < 8) sC2[ab * 8 + i] = f2bf(v); else sC2b[ab] = f2bf(v);
    }
    // ---- build C1 (f32) ----
    for (int e = tid; e < 81; e += 64) {
        int a = e / 9; int i = e - a * 9;
        float v;
        if (i == 0)     v = dotc<1, 1>(p.U1[0] + a,               p.W1[0] + s * C_CH + c);
        else if (i < 4) v = dotc<1, 3>(p.U1[1] + a * 3 + (i - 1), p.W1[1] + s * C_CH + c);
        else            v = dotc<1, 5>(p.U1[2] + a * 5 + (i - 4), p.W1[2] + s * C_CH + c);
        if (i < 8) sC1[a * 8 + i] = v; else sC1b[a] = v;
    }
    __syncthreads();

    const int cnt = counts[s];
    const uint4*  C3v = (const uint4*)sC3;
    const uint4*  C2v = (const uint4*)sC2;
    const float4* C1v = (const float4*)sC1;

    for (int base = h * 128; base < cnt; base += 256) {
        int m[2];
        float x[2][9];
#pragma unroll
        for (int pn = 0; pn < 2; ++pn) {
            int idx = base + pn * 64 + tid;
            m[pn] = (idx < cnt) ? lists[s * N_NODES + idx] : -1;
            const float* xp = nf + ((long)(m[pn] < 0 ? 0 : m[pn]) * C_CH + c) * 9;
#pragma unroll
            for (int j = 0; j < 9; ++j) x[pn][j] = xp[j];
        }

        float o[2][9];
#pragma unroll
        for (int pn = 0; pn < 2; ++pn)
#pragma unroll
            for (int i = 0; i < 9; ++i) o[pn][i] = 0.f;

#pragma unroll 1
        for (int a = 0; a < 9; ++a) {
            const float xa0 = selx(x[0], a);
            const float xa1 = selx(x[1], a);

            // ta init from C1 row (f32)
            float ta[2][9];
            {
                float4 lo = C1v[a * 2], hi = C1v[a * 2 + 1];
                float c1[9] = {lo.x, lo.y, lo.z, lo.w, hi.x, hi.y, hi.z, hi.w, sC1b[a]};
#pragma unroll
                for (int i = 0; i < 9; ++i) { ta[0][i] = c1[i]; ta[1][i] = c1[i]; }
            }

            // quadratic term: b = 0..8 (compile-time b)
#pragma unroll
            for (int b = 0; b < 9; ++b) {
                const int ab = a * 9 + b;
                uint4 r = C2v[ab];
                float cc[9];
                cc[0] = bf_lo(r.x); cc[1] = bf_hi(r.x);
                cc[2] = bf_lo(r.y); cc[3] = bf_hi(r.y);
                cc[4] = bf_lo(r.z); cc[5] = bf_hi(r.z);
                cc[6] = bf_lo(r.w); cc[7] = bf_hi(r.w);
                cc[8] = bf_up(sC2b[ab]);
#pragma unroll
                for (int i = 0; i < 9; ++i) {
                    ta[0][i] = __builtin_fmaf(cc[i], x[0][b], ta[0][i]);
                    ta[1][i] = __builtin_fmaf(cc[i], x[1][b], ta[1][i]);
                }
            }

            // cubic term: symmetric (b<=j) triangle, all compile-time
#pragma unroll
            for (int b = 0; b < 9; ++b) {
#pragma unroll
                for (int j = b; j < 9; ++j) {
                    const int m3 = a * NTRI + tri(b, j);
                    uint4 r = C3v[m3];
                    float cc[9];
                    cc[0] = bf_lo(r.x); cc[1] = bf_hi(r.x);
                    cc[2] = bf_lo(r.y); cc[3] = bf_hi(r.y);
                    cc[4] = bf_lo(r.z); cc[5] = bf_hi(r.z);
                    cc[6] = bf_lo(r.w); cc[7] = bf_hi(r.w);
                    cc[8] = bf_up(sC3b[m3]);
                    const float p0 = x[0][b] * x[0][j];
                    const float p1 = x[1][b] * x[1][j];
#pragma unroll
                    for (int i = 0; i < 9; ++i) {
                        ta[0][i] = __builtin_fmaf(cc[i], p0, ta[0][i]);
                        ta[1][i] = __builtin_fmaf(cc[i], p1, ta[1][i]);
                    }
                }
            }

#pragma unroll
            for (int i = 0; i < 9; ++i) {
                o[0][i] = __builtin_fmaf(ta[0][i], xa0, o[0][i]);
                o[1][i] = __builtin_fmaf(ta[1][i], xa1, o[1][i]);
            }
        }

#pragma unroll
        for (int pn = 0; pn < 2; ++pn) {
            if (m[pn] >= 0) {
                float* op = out + ((long)m[pn] * C_CH + c) * 9;
#pragma unroll
                for (int i = 0; i < 9; ++i) op[i] = o[pn][i];
            }
        }
    }
}

// ---------------------------------------------------------------------------
extern "C" void kernel_launch(void* const* d_in, const int* in_sizes, int n_in,
                              void* d_out, int out_size, void* d_ws, size_t ws_size,
                              hipStream_t stream) {
    const float* nf  = (const float*)d_in[0];
    const int* index = (const int*)d_in[1];

    const float* U3_0e = (const float*)d_in[2];
    const float* U3_1o = (const float*)d_in[4];
    const float* U3_2e = (const float*)d_in[6];

    Params p;
    p.W3[0] = (const float*)d_in[3];
    p.W3[1] = (const float*)d_in[5];
    p.W3[2] = (const float*)d_in[7];
    p.U2[0] = (const float*)d_in[8];  p.W2[0] = (const float*)d_in[9];
    p.U2[1] = (const float*)d_in[10]; p.W2[1] = (const float*)d_in[11];
    p.U2[2] = (const float*)d_in[12]; p.W2[2] = (const float*)d_in[13];
    p.U1[0] = (const float*)d_in[14]; p.W1[0] = (const float*)d_in[15];
    p.U1[1] = (const float*)d_in[16]; p.W1[1] = (const float*)d_in[17];
    p.U1[2] = (const float*)d_in[18]; p.W1[2] = (const float*)d_in[19];

    int* counts = (int*)d_ws;
    int* lists  = (int*)d_ws + 16;
    float* Up   = (float*)d_ws + WS_UP_OFF;

    bucket_kernel<<<1, 1024, 0, stream>>>(index, counts, lists);
    presym_kernel<<<(43740 + 255) / 256, 256, 0, stream>>>(U3_0e, U3_1o, U3_2e, Up);
    eval_kernel<<<N_SPEC * C_CH * 2, 64, 0, stream>>>(nf, counts, lists, Up, p, (float*)d_out);
}